// Round 13
// baseline (2754.718 us; speedup 1.0000x reference)
//
#include <hip/hip_runtime.h>

// GRU encoder-decoder, MFMA split-precision, K-split wave pairs (r13 = r12
// + pins hoisted out of the time loop + wave-uniform ex selects).
// r12 counters: VALUBusy 68.7% = ~1750 VALU inst/wave/step vs ~400 in
// source -> the per-step 18x asm volatile "+a" pins were 18 scheduler
// barriers/step and forced AGPR<->VGPR shuttling. Fix: pin ONCE per phase
// after the weight load (opaque value definition kills remat permanently,
// zero per-step cost); ex-store row-block selection via wave-uniform
// if(kf) branch instead of 28 v_cndmask/step.
// B=8192, H=64, 512 enc + 180 dec steps. 256 blocks x 512 threads (8 waves),
// 32 batches/block, 1 block/CU -> 2 waves/SIMD. Wave (g,kf) owns N-tiles
// {g,4+g,8+g} and K-half kf: 18 weight frags = 72 AGPR; live ~200 <= 256.
// Each wave computes partials for BOTH 16-batch row-blocks; kf-pair
// exchanges the other row-block via lane-aligned LDS f32x4 (identical
// C-layout across the pair); wave kf gates row-block kf. 4-barrier step
// skeleton (r9/r10/r12-proven safe). h fp32 in gate lanes; bf16 hi/lo
// A-frags in LDS (XOR b^rg swizzle, 0 conflicts).

typedef __attribute__((ext_vector_type(8))) short bf16x8;
typedef __attribute__((ext_vector_type(4))) float f32x4;

struct Params {
  const float *x;
  const float *wih0e, *bih0e, *bhh0e, *bih1e, *bhh1e;
  const float *wih0d, *bih0d, *bhh0d, *bih1d, *bhh1d;
  const float *outW, *outb;
  const unsigned short *wt;   // [6][12 nt][2 kf][2 sp][64 lane][8 e] bf16 frags
  float *out;
};

__device__ __forceinline__ float sgm(float v) { return 1.f / (1.f + __expf(-v)); }
__device__ __forceinline__ float th(float v)  { float e = __expf(2.f * v); return 1.f - 2.f / (e + 1.f); }

__device__ __forceinline__ unsigned short rbf(float v) {
  unsigned int u = __float_as_uint(v);
  return (unsigned short)((u + 0x7fffu + ((u >> 16) & 1u)) >> 16);
}
__device__ __forceinline__ float ubf(unsigned short h) {
  return __uint_as_float((unsigned int)h << 16);
}

__device__ __forceinline__ f32x4 mfma16(bf16x8 a, bf16x8 b, f32x4 c) {
  return __builtin_amdgcn_mfma_f32_16x16x32_bf16(a, b, c, 0, 0, 0);
}

// Preprocess the six 192x64 fp32 matrices into B-fragment bf16 hi/lo planes.
// B[k][n] = W[n][k]; frag (nt,kf,sp): lane l elem e holds
// B[k = kf*32 + (l>>4)*8 + e][n = nt*16 + (l&15)].
// Flat: dst[m][ ((nt*2+kf)*2+sp)*512 + l*8 + e ]   (validated r3-r12)
__global__ void prep_w(const float* s0, const float* s1, const float* s2,
                       const float* s3, const float* s4, const float* s5,
                       unsigned short* dst) {
  const float* srcs[6] = {s0, s1, s2, s3, s4, s5};
  const float* s = srcs[blockIdx.x];
  unsigned short* o = dst + blockIdx.x * 24576;
  for (int i = threadIdx.x; i < 24576; i += blockDim.x) {
    int e  = i & 7;
    int l  = (i >> 3) & 63;
    int sp = (i >> 9) & 1;
    int kf = (i >> 10) & 1;
    int nt = i >> 11;
    int n = nt * 16 + (l & 15);
    int k = kf * 32 + (l >> 4) * 8 + e;
    float v = s[n * 64 + k];
    unsigned short hi = rbf(v);
    unsigned short val = hi;
    if (sp) val = rbf(v - ubf(hi));
    o[i] = val;
  }
}

// A-frag LDS layout per (parity, rb): 2048 ushorts:
//   idx(kf,sp,rg,bslot,e) = (kf*2+sp)*512 + rg*128 + bslot*8 + e
//   value = h_split[sp][b16 = bslot ^ rg][k = kf*32 + rg*8 + e]
// Read (lane l, wave kf): base kf*1024 + rg*128 + ((jc^rg)<<3) -> b128 linear.
// Write (j-owner): kfj=j>>5, rgj=(j>>3)&3, ej=j&7, bslot=b16^rgj -> <=2-way.

__global__ __launch_bounds__(512, 2) void gru_main(Params p) {
  __shared__ unsigned short aH0[2][2][2048];   // [parity][rb][idx]
  __shared__ unsigned short aH1[2][2][2048];
  __shared__ f32x4 ex[8][7][64];               // [wave][acc slot][lane]
  __shared__ float pw[4][32];                  // [g][local batch]

  const int tid = threadIdx.x;
  const int l   = tid & 63;
  const int w   = tid >> 6;        // wave 0..7
  const int g   = w & 3;           // N-tile group
  const int kf  = w >> 2;          // K-half owned AND row-block gated
  const int jc  = l & 15;
  const int rg  = l >> 4;
  const int j   = g * 16 + jc;     // this lane's hidden/gate index
  const int b0  = blockIdx.x * 32;
  const int bloc = kf * 16 + rg * 4;   // gated local batch base (+i)

  const int kfj = j >> 5, rgj = (j >> 3) & 3, ej = j & 7;
  const int wbase = kf * 2048 + kfj * 1024 + rgj * 128 + ej; // gated rb folded in
  const int rdb = kf * 1024 + rg * 128 + ((jc ^ rg) << 3);   // own-kf frag base

  for (int i = tid; i < 8192; i += 512) {
    ((unsigned short*)aH0)[i] = 0;
    ((unsigned short*)aH1)[i] = 0;
  }
  float h0own[4] = {0.f, 0.f, 0.f, 0.f}, h1own[4] = {0.f, 0.f, 0.f, 0.f};

  bf16x8 wB[3][3][2];   // [matrix][gate][split], kf fixed - AGPR (72 regs)

  for (int ph = 0; ph < 2; ++ph) {
    // ---- load this phase's weight fragments (own kf only) ----
#pragma unroll
    for (int m = 0; m < 3; ++m)
#pragma unroll
      for (int gt = 0; gt < 3; ++gt)
#pragma unroll
        for (int sp = 0; sp < 2; ++sp) {
          int nt = gt * 4 + g;
          wB[m][gt][sp] = *(const bf16x8*)(p.wt +
              (((((ph * 3 + m) * 12 + nt) * 2 + kf) * 2 + sp) << 9) + l * 8);
        }
    // ---- pin ONCE per phase: opaque redefinition kills the load chain,
    //      so remat is impossible for the whole t-loop; zero per-step cost.
#pragma unroll
    for (int m = 0; m < 3; ++m)
#pragma unroll
      for (int gt = 0; gt < 3; ++gt)
#pragma unroll
        for (int sp = 0; sp < 2; ++sp)
          asm volatile("" : "+a"(wB[m][gt][sp]));

    // ---- per-lane constants for row j ----
    float bi0[3], bh0[3], bi1[3], bh1[3], wxa[3], wxb[3];
#pragma unroll
    for (int gt = 0; gt < 3; ++gt) {
      int r = gt * 64 + j;
      if (ph == 0) {
        bi0[gt] = p.bih0e[r]; bh0[gt] = p.bhh0e[r];
        bi1[gt] = p.bih1e[r]; bh1[gt] = p.bhh1e[r];
        wxa[gt] = p.wih0e[2 * r]; wxb[gt] = p.wih0e[2 * r + 1];
      } else {
        bi0[gt] = p.bih0d[r]; bh0[gt] = p.bhh0d[r];
        bi1[gt] = p.bih1d[r]; bh1[gt] = p.bhh1d[r];
        wxa[gt] = p.wih0d[r]; wxb[gt] = 0.f;
      }
    }
    const float oW = p.outW[j], ob = p.outb[0];
    const int T = ph ? 180 : 512;
    __syncthreads();

    for (int t = 0; t < T; ++t) {
      const int cur = t & 1;
      const unsigned short* h0o = &aH0[cur ^ 1][0][0];
      const unsigned short* h1o = &aH1[cur ^ 1][0][0];
      unsigned short* h0n = &aH0[cur][0][0];
      unsigned short* h1n = &aH1[cur][0][0];

      // ======== R1: cell0 partials, both row-blocks, own kf ========
      f32x4 aR0 = {0,0,0,0}, aZ0 = {0,0,0,0}, aN0 = {0,0,0,0};
      f32x4 aR1 = {0,0,0,0}, aZ1 = {0,0,0,0}, aN1 = {0,0,0,0};
      {
        bf16x8 ah0 = *(const bf16x8*)&h0o[rdb];
        bf16x8 al0 = *(const bf16x8*)&h0o[rdb + 512];
        bf16x8 ah1 = *(const bf16x8*)&h0o[2048 + rdb];
        bf16x8 al1 = *(const bf16x8*)&h0o[2048 + rdb + 512];
        aR0 = mfma16(ah0, wB[0][0][0], aR0);
        aR1 = mfma16(ah1, wB[0][0][0], aR1);
        aZ0 = mfma16(ah0, wB[0][1][0], aZ0);
        aZ1 = mfma16(ah1, wB[0][1][0], aZ1);
        aN0 = mfma16(ah0, wB[0][2][0], aN0);
        aN1 = mfma16(ah1, wB[0][2][0], aN1);
        aR0 = mfma16(al0, wB[0][0][0], aR0);
        aR1 = mfma16(al1, wB[0][0][0], aR1);
        aZ0 = mfma16(al0, wB[0][1][0], aZ0);
        aZ1 = mfma16(al1, wB[0][1][0], aZ1);
        aN0 = mfma16(al0, wB[0][2][0], aN0);
        aN1 = mfma16(al1, wB[0][2][0], aN1);
        aR0 = mfma16(ah0, wB[0][0][1], aR0);
        aR1 = mfma16(ah1, wB[0][0][1], aR1);
        aZ0 = mfma16(ah0, wB[0][1][1], aZ0);
        aZ1 = mfma16(ah1, wB[0][1][1], aZ1);
        aN0 = mfma16(ah0, wB[0][2][1], aN0);
        aN1 = mfma16(ah1, wB[0][2][1], aN1);
      }
      // export the row-block we do NOT gate (rb = kf^1); wave-uniform branch
      if (kf) {
        ex[w][0][l] = aR0; ex[w][1][l] = aZ0; ex[w][2][l] = aN0;
      } else {
        ex[w][0][l] = aR1; ex[w][1][l] = aZ1; ex[w][2][l] = aN1;
      }
      __syncthreads();   // ---- A: ex(cell0) ready ----

      // ======== R2: gate0 for own row-block (rb = kf) ========
      float2 xx[4]; float prevv[4];
      if (ph == 0) {
#pragma unroll
        for (int i = 0; i < 4; ++i)
          xx[i] = *(const float2*)(p.x + ((size_t)(b0 + bloc + i) * 512 + t) * 2);
      } else if (t > 0) {
#pragma unroll
        for (int i = 0; i < 4; ++i)
          prevv[i] = ob + pw[0][bloc + i] + pw[1][bloc + i]
                        + pw[2][bloc + i] + pw[3][bloc + i];
        if (g == 0 && jc == 0) {
#pragma unroll
          for (int i = 0; i < 4; ++i)
            p.out[(size_t)(b0 + bloc + i) * 180 + (t - 1)] = prevv[i];
        }
      } else {
#pragma unroll
        for (int i = 0; i < 4; ++i) prevv[i] = 0.f;
      }
      {
        f32x4 sR, sZ, sN;
        if (kf) { sR = aR1; sZ = aZ1; sN = aN1; }
        else    { sR = aR0; sZ = aZ0; sN = aN0; }
        f32x4 pR = ex[w ^ 4][0][l];    // partner's partial for our rb
        f32x4 pZ = ex[w ^ 4][1][l];
        f32x4 pN = ex[w ^ 4][2][l];
#pragma unroll
        for (int i = 0; i < 4; ++i) {
          float xr, xz, xn;
          if (ph == 0) {
            xr = bi0[0] + wxa[0] * xx[i].x + wxb[0] * xx[i].y;
            xz = bi0[1] + wxa[1] * xx[i].x + wxb[1] * xx[i].y;
            xn = bi0[2] + wxa[2] * xx[i].x + wxb[2] * xx[i].y;
          } else {
            xr = bi0[0] + wxa[0] * prevv[i];
            xz = bi0[1] + wxa[1] * prevv[i];
            xn = bi0[2] + wxa[2] * prevv[i];
          }
          float r = sgm(xr + bh0[0] + sR[i] + pR[i]);
          float z = sgm(xz + bh0[1] + sZ[i] + pZ[i]);
          float n = th(xn + r * (bh0[2] + sN[i] + pN[i]));
          h0own[i] = (1.f - z) * n + z * h0own[i];
          unsigned short hi = rbf(h0own[i]);
          unsigned short lo = rbf(h0own[i] - ubf(hi));
          int idx = wbase + (((rg * 4 + i) ^ rgj) << 3);
          h0n[idx] = hi; h0n[idx + 512] = lo;
        }
      }
      __syncthreads();   // ---- B: h0(new) frags complete ----

      // ======== R3: cell1 partials, both row-blocks, own kf ========
      f32x4 cR0 = {0,0,0,0}, cZ0 = {0,0,0,0}, iN0 = {0,0,0,0}, hN0 = {0,0,0,0};
      f32x4 cR1 = {0,0,0,0}, cZ1 = {0,0,0,0}, iN1 = {0,0,0,0}, hN1 = {0,0,0,0};
      {
        bf16x8 gh0 = *(const bf16x8*)&h0n[rdb];
        bf16x8 gl0 = *(const bf16x8*)&h0n[rdb + 512];
        bf16x8 gh1 = *(const bf16x8*)&h0n[2048 + rdb];
        bf16x8 gl1 = *(const bf16x8*)&h0n[2048 + rdb + 512];
        bf16x8 qh0 = *(const bf16x8*)&h1o[rdb];
        bf16x8 ql0 = *(const bf16x8*)&h1o[rdb + 512];
        bf16x8 qh1 = *(const bf16x8*)&h1o[2048 + rdb];
        bf16x8 ql1 = *(const bf16x8*)&h1o[2048 + rdb + 512];
        cR0 = mfma16(gh0, wB[1][0][0], cR0);
        cR1 = mfma16(gh1, wB[1][0][0], cR1);
        cZ0 = mfma16(gh0, wB[1][1][0], cZ0);
        cZ1 = mfma16(gh1, wB[1][1][0], cZ1);
        iN0 = mfma16(gh0, wB[1][2][0], iN0);
        iN1 = mfma16(gh1, wB[1][2][0], iN1);
        cR0 = mfma16(qh0, wB[2][0][0], cR0);
        cR1 = mfma16(qh1, wB[2][0][0], cR1);
        cZ0 = mfma16(qh0, wB[2][1][0], cZ0);
        cZ1 = mfma16(qh1, wB[2][1][0], cZ1);
        hN0 = mfma16(qh0, wB[2][2][0], hN0);
        hN1 = mfma16(qh1, wB[2][2][0], hN1);
        cR0 = mfma16(gl0, wB[1][0][0], cR0);
        cR1 = mfma16(gl1, wB[1][0][0], cR1);
        cZ0 = mfma16(gl0, wB[1][1][0], cZ0);
        cZ1 = mfma16(gl1, wB[1][1][0], cZ1);
        iN0 = mfma16(gl0, wB[1][2][0], iN0);
        iN1 = mfma16(gl1, wB[1][2][0], iN1);
        cR0 = mfma16(ql0, wB[2][0][0], cR0);
        cR1 = mfma16(ql1, wB[2][0][0], cR1);
        cZ0 = mfma16(ql0, wB[2][1][0], cZ0);
        cZ1 = mfma16(ql1, wB[2][1][0], cZ1);
        hN0 = mfma16(ql0, wB[2][2][0], hN0);
        hN1 = mfma16(ql1, wB[2][2][0], hN1);
        cR0 = mfma16(gh0, wB[1][0][1], cR0);
        cR1 = mfma16(gh1, wB[1][0][1], cR1);
        cZ0 = mfma16(gh0, wB[1][1][1], cZ0);
        cZ1 = mfma16(gh1, wB[1][1][1], cZ1);
        iN0 = mfma16(gh0, wB[1][2][1], iN0);
        iN1 = mfma16(gh1, wB[1][2][1], iN1);
        cR0 = mfma16(qh0, wB[2][0][1], cR0);
        cR1 = mfma16(qh1, wB[2][0][1], cR1);
        cZ0 = mfma16(qh0, wB[2][1][1], cZ0);
        cZ1 = mfma16(qh1, wB[2][1][1], cZ1);
        hN0 = mfma16(qh0, wB[2][2][1], hN0);
        hN1 = mfma16(qh1, wB[2][2][1], hN1);
      }
      if (kf) {
        ex[w][3][l] = cR0; ex[w][4][l] = cZ0;
        ex[w][5][l] = iN0; ex[w][6][l] = hN0;
      } else {
        ex[w][3][l] = cR1; ex[w][4][l] = cZ1;
        ex[w][5][l] = iN1; ex[w][6][l] = hN1;
      }
      __syncthreads();   // ---- C: ex(cell1) ready ----

      // ======== R4: gate1 for own row-block ========
      {
        f32x4 sR, sZ, sI, sH;
        if (kf) { sR = cR1; sZ = cZ1; sI = iN1; sH = hN1; }
        else    { sR = cR0; sZ = cZ0; sI = iN0; sH = hN0; }
        f32x4 pR = ex[w ^ 4][3][l];
        f32x4 pZ = ex[w ^ 4][4][l];
        f32x4 pI = ex[w ^ 4][5][l];
        f32x4 pH = ex[w ^ 4][6][l];
        float v[4];
#pragma unroll
        for (int i = 0; i < 4; ++i) {
          float r = sgm(sR[i] + pR[i] + bi1[0] + bh1[0]);
          float z = sgm(sZ[i] + pZ[i] + bi1[1] + bh1[1]);
          float n = th(sI[i] + pI[i] + bi1[2] + r * (bh1[2] + sH[i] + pH[i]));
          h1own[i] = (1.f - z) * n + z * h1own[i];
          unsigned short hi = rbf(h1own[i]);
          unsigned short lo = rbf(h1own[i] - ubf(hi));
          int idx = wbase + (((rg * 4 + i) ^ rgj) << 3);
          h1n[idx] = hi; h1n[idx + 512] = lo;
          v[i] = oW * h1own[i];
        }
        if (ph == 1) {
          // reduce over this wave's 16 jc lanes (within each rg group)
#pragma unroll
          for (int off = 1; off < 16; off <<= 1)
#pragma unroll
            for (int i = 0; i < 4; ++i) v[i] += __shfl_xor(v[i], off, 64);
          if (jc == 0) {
#pragma unroll
            for (int i = 0; i < 4; ++i) pw[g][bloc + i] = v[i];
          }
        }
      }
      __syncthreads();   // ---- D: end-of-step fence (proven skeleton) ----
    }
    // ---- decoder tail: emit out[179] ----
    if (ph == 1) {
      if (g == 0 && jc == 0) {
#pragma unroll
        for (int i = 0; i < 4; ++i) {
          float fv = ob + pw[0][bloc + i] + pw[1][bloc + i]
                        + pw[2][bloc + i] + pw[3][bloc + i];
          p.out[(size_t)(b0 + bloc + i) * 180 + 179] = fv;
        }
      }
    }
  }
}

extern "C" void kernel_launch(void* const* d_in, const int* in_sizes, int n_in,
                              void* d_out, int out_size, void* d_ws, size_t ws_size,
                              hipStream_t stream) {
  // input order: 0 x, 1 enc_Wih0, 2 enc_Whh0, 3 enc_bih0, 4 enc_bhh0,
  // 5 enc_Wih1, 6 enc_Whh1, 7 enc_bih1, 8 enc_bhh1, 9 dec_Wih0, 10 dec_Whh0,
  // 11 dec_bih0, 12 dec_bhh0, 13 dec_Wih1, 14 dec_Whh1, 15 dec_bih1,
  // 16 dec_bhh1, 17 out_W, 18 out_b
  unsigned short* wt = (unsigned short*)d_ws;  // 6*24576*2 = 294912 B

  prep_w<<<dim3(6), dim3(256), 0, stream>>>(
      (const float*)d_in[2], (const float*)d_in[5], (const float*)d_in[6],
      (const float*)d_in[10], (const float*)d_in[13], (const float*)d_in[14], wt);

  Params p;
  p.x = (const float*)d_in[0];
  p.wih0e = (const float*)d_in[1];
  p.bih0e = (const float*)d_in[3];
  p.bhh0e = (const float*)d_in[4];
  p.bih1e = (const float*)d_in[7];
  p.bhh1e = (const float*)d_in[8];
  p.wih0d = (const float*)d_in[9];
  p.bih0d = (const float*)d_in[11];
  p.bhh0d = (const float*)d_in[12];
  p.bih1d = (const float*)d_in[15];
  p.bhh1d = (const float*)d_in[16];
  p.outW = (const float*)d_in[17];
  p.outb = (const float*)d_in[18];
  p.wt = wt;
  p.out = (float*)d_out;

  gru_main<<<dim3(256), dim3(512), 0, stream>>>(p);
}

// Round 14
// 2121.328 us; speedup vs baseline: 1.2986x; 1.2986x over previous
//
#include <hip/hip_runtime.h>

// GRU encoder-decoder, MFMA split-precision, ownership-aligned (r14 = r5
// base — the best-known kernel, 2158us harness — with ONE change: the 36
// weight-fragment pins are hoisted out of the time loop to once-per-phase.
// r5 executed them per-step: each "+v" pin demanded the value in the
// 128-reg arch-VGPR region at that point -> AGPR<->VGPR shuttle every step
// (r6 diagnosis; r5 WRITE_SIZE 27MB, VALUBusy 69%). A one-time pin still
// kills remat (opaque redefinition) but frees the allocator to keep the
// frags in AGPRs across the whole loop. r6-r13 structural redesigns
// (1-wave ILP, partial-AGPR, K-split pairs) all benched WORSE than r5;
// this is the minimal validated delta on the best base.
// B=8192, H=64, 512 enc + 180 dec steps. 512 blocks x 256 threads (4 waves),
// 16 batches/block, 2 waves/SIMD. Wave w owns N-tiles {w,4+w,8+w}; lane
// (rg,jc) gates (batch 4rg+i, j=16w+jc) lane-locally; no score exchange;
// 2 barriers/step; bf16 hi/lo A-frags in LDS (XOR b^rg swizzle, 0
// conflicts); cell1 r/z accumulators merged across its two GEMMs.

typedef __attribute__((ext_vector_type(8))) short bf16x8;
typedef __attribute__((ext_vector_type(4))) float f32x4;

struct Params {
  const float *x;
  const float *wih0e, *bih0e, *bhh0e, *bih1e, *bhh1e;
  const float *wih0d, *bih0d, *bhh0d, *bih1d, *bhh1d;
  const float *outW, *outb;
  const unsigned short *wt;   // [6][12 nt][2 kf][2 sp][64 lane][8 e] bf16 frags
  float *out;
};

__device__ __forceinline__ float sgm(float v) { return 1.f / (1.f + __expf(-v)); }
__device__ __forceinline__ float th(float v)  { float e = __expf(2.f * v); return 1.f - 2.f / (e + 1.f); }

// fp32 -> bf16 round-to-nearest-even (bit trick)
__device__ __forceinline__ unsigned short rbf(float v) {
  unsigned int u = __float_as_uint(v);
  return (unsigned short)((u + 0x7fffu + ((u >> 16) & 1u)) >> 16);
}
__device__ __forceinline__ float ubf(unsigned short h) {
  return __uint_as_float((unsigned int)h << 16);
}

__device__ __forceinline__ f32x4 mfma16(bf16x8 a, bf16x8 b, f32x4 c) {
  return __builtin_amdgcn_mfma_f32_16x16x32_bf16(a, b, c, 0, 0, 0);
}

// Preprocess the six 192x64 fp32 matrices into B-fragment bf16 hi/lo planes.
// B[k][n] = W[n][k]; frag (nt,kf,sp): lane l elem e holds
// B[k = kf*32 + (l>>4)*8 + e][n = nt*16 + (l&15)].
// Flat: dst[m][ ((nt*2+kf)*2+sp)*512 + l*8 + e ]   (validated r3-r13)
__global__ void prep_w(const float* s0, const float* s1, const float* s2,
                       const float* s3, const float* s4, const float* s5,
                       unsigned short* dst) {
  const float* srcs[6] = {s0, s1, s2, s3, s4, s5};
  const float* s = srcs[blockIdx.x];
  unsigned short* o = dst + blockIdx.x * 24576;
  for (int i = threadIdx.x; i < 24576; i += blockDim.x) {
    int e  = i & 7;
    int l  = (i >> 3) & 63;
    int sp = (i >> 9) & 1;
    int kf = (i >> 10) & 1;
    int nt = i >> 11;
    int n = nt * 16 + (l & 15);
    int k = kf * 32 + (l >> 4) * 8 + e;
    float v = s[n * 64 + k];
    unsigned short hi = rbf(v);
    unsigned short val = hi;
    if (sp) val = rbf(v - ubf(hi));
    o[i] = val;
  }
}

// A-frag LDS layout (per h matrix, per parity buffer), 2048 ushorts = 4KB:
//   idx(kf,sp,rg,bslot,e) = (kf*2+sp)*512 + rg*128 + bslot*8 + e
//   value = h_split[sp][b = bslot ^ rg][k = kf*32 + rg*8 + e]
// Read (lane l): rg=l>>4, bslot=(l&15)^rg -> b128, quarter-wave linear.
// Write (j-owner): kf=j>>5, rg=(j>>3)&3, e=j&7, bslot=b^rg -> <=2-way.

__global__ __launch_bounds__(256, 2) void gru_main(Params p) {
  __shared__ unsigned short aH0[2][2048];
  __shared__ unsigned short aH1[2][2048];
  __shared__ float pw[4][16];

  const int tid = threadIdx.x;
  const int l   = tid & 63;
  const int w   = tid >> 6;        // wave 0..3
  const int jc  = l & 15;
  const int rg  = l >> 4;
  const int j   = w * 16 + jc;     // this lane's hidden/gate index
  const int b0  = blockIdx.x * 16;

  const int kfj = j >> 5, rgj = (j >> 3) & 3, ej = j & 7;
  const int wbase = kfj * 1024 + rgj * 128 + ej;   // +bslot*8; +512 for lo
  const int rdb = rg * 128 + ((jc ^ rg) << 3);

  for (int i = tid; i < 2048; i += 256) {
    aH0[0][i] = 0; aH0[1][i] = 0; aH1[0][i] = 0; aH1[1][i] = 0;
  }
  float h0own[4] = {0.f, 0.f, 0.f, 0.f}, h1own[4] = {0.f, 0.f, 0.f, 0.f};

  bf16x8 wB[3][3][2][2];   // [matrix][gate g][kf][split] persistent

  for (int ph = 0; ph < 2; ++ph) {
    // ---- load this phase's weight fragments; tile for gate g is g*4+w ----
#pragma unroll
    for (int m = 0; m < 3; ++m)
#pragma unroll
      for (int g = 0; g < 3; ++g)
#pragma unroll
        for (int kf = 0; kf < 2; ++kf)
#pragma unroll
          for (int sp = 0; sp < 2; ++sp) {
            int nt = g * 4 + w;
            wB[m][g][kf][sp] = *(const bf16x8*)(p.wt +
                (((((ph * 3 + m) * 12 + nt) * 2 + kf) * 2 + sp) << 9) + l * 8);
          }
    // ---- pin ONCE per phase (hoisted from per-step in r5): opaque
    //      redefinition kills the load chain -> remat impossible for the
    //      whole t-loop; allocator free to keep frags in AGPRs (no shuttle).
#pragma unroll
    for (int m = 0; m < 3; ++m)
#pragma unroll
      for (int g = 0; g < 3; ++g)
#pragma unroll
        for (int kf = 0; kf < 2; ++kf)
#pragma unroll
          for (int sp = 0; sp < 2; ++sp)
            asm volatile("" : "+v"(wB[m][g][kf][sp]));

    // ---- per-lane constants for row j ----
    float bi0[3], bh0[3], bi1[3], bh1[3], wxa[3], wxb[3];
#pragma unroll
    for (int g = 0; g < 3; ++g) {
      int r = g * 64 + j;
      if (ph == 0) {
        bi0[g] = p.bih0e[r]; bh0[g] = p.bhh0e[r];
        bi1[g] = p.bih1e[r]; bh1[g] = p.bhh1e[r];
        wxa[g] = p.wih0e[2 * r]; wxb[g] = p.wih0e[2 * r + 1];
      } else {
        bi0[g] = p.bih0d[r]; bh0[g] = p.bhh0d[r];
        bi1[g] = p.bih1d[r]; bh1[g] = p.bhh1d[r];
        wxa[g] = p.wih0d[r]; wxb[g] = 0.f;
      }
    }
    const float oW = p.outW[j], ob = p.outb[0];
    const int T = ph ? 180 : 512;
    __syncthreads();

    for (int t = 0; t < T; ++t) {
      const int cur = t & 1;
      // ---- inputs: x (enc) / prev from pw partials (dec) ----
      float2 xx[4]; float prevv[4];
      if (ph == 0) {
#pragma unroll
        for (int i = 0; i < 4; ++i)
          xx[i] = *(const float2*)(p.x + ((size_t)(b0 + rg * 4 + i) * 512 + t) * 2);
      } else {
        if (t > 0) {
#pragma unroll
          for (int i = 0; i < 4; ++i)
            prevv[i] = ob + pw[0][rg * 4 + i] + pw[1][rg * 4 + i]
                          + pw[2][rg * 4 + i] + pw[3][rg * 4 + i];
          if (w == 0 && jc == 0) {
#pragma unroll
            for (int i = 0; i < 4; ++i)
              p.out[(size_t)(b0 + rg * 4 + i) * 180 + (t - 1)] = prevv[i];
          }
        } else {
#pragma unroll
          for (int i = 0; i < 4; ++i) prevv[i] = 0.f;
        }
      }
      // ---- cell0 GEMM: Whh0 . h0(old); 3 lane-local gate accumulators ----
      const unsigned short* h0o = aH0[cur ^ 1];
      f32x4 aR = {0,0,0,0}, aZ = {0,0,0,0}, aN = {0,0,0,0};
#pragma unroll
      for (int kf = 0; kf < 2; ++kf) {
        bf16x8 ah = *(const bf16x8*)&h0o[kf * 1024 + rdb];
        bf16x8 al = *(const bf16x8*)&h0o[kf * 1024 + 512 + rdb];
        aR = mfma16(ah, wB[0][0][kf][0], aR);
        aZ = mfma16(ah, wB[0][1][kf][0], aZ);
        aN = mfma16(ah, wB[0][2][kf][0], aN);
        aR = mfma16(al, wB[0][0][kf][0], aR);
        aZ = mfma16(al, wB[0][1][kf][0], aZ);
        aN = mfma16(al, wB[0][2][kf][0], aN);
        aR = mfma16(ah, wB[0][0][kf][1], aR);
        aZ = mfma16(ah, wB[0][1][kf][1], aZ);
        aN = mfma16(ah, wB[0][2][kf][1], aN);
      }
      // ---- gate0 (lane-local), publish h0(new) frags ----
      unsigned short* h0n = aH0[cur];
#pragma unroll
      for (int i = 0; i < 4; ++i) {
        float xr, xz, xn;
        if (ph == 0) {
          xr = bi0[0] + wxa[0] * xx[i].x + wxb[0] * xx[i].y;
          xz = bi0[1] + wxa[1] * xx[i].x + wxb[1] * xx[i].y;
          xn = bi0[2] + wxa[2] * xx[i].x + wxb[2] * xx[i].y;
        } else {
          xr = bi0[0] + wxa[0] * prevv[i];
          xz = bi0[1] + wxa[1] * prevv[i];
          xn = bi0[2] + wxa[2] * prevv[i];
        }
        float r = sgm(xr + bh0[0] + aR[i]);
        float z = sgm(xz + bh0[1] + aZ[i]);
        float n = th(xn + r * (bh0[2] + aN[i]));
        h0own[i] = (1.f - z) * n + z * h0own[i];
        unsigned short hi = rbf(h0own[i]);
        unsigned short lo = rbf(h0own[i] - ubf(hi));
        int idx = wbase + (((rg * 4 + i) ^ rgj) << 3);
        h0n[idx] = hi; h0n[idx + 512] = lo;
      }
      __syncthreads();   // mid: h0(new) frags complete
      // ---- cell1 dual GEMM: Wih1 . h0(new) ; Whh1 . h1(old) ----
      // r/z accumulators merged across both GEMMs (outputs summed anyway)
      const unsigned short* h1o = aH1[cur ^ 1];
      f32x4 cR = {0,0,0,0}, cZ = {0,0,0,0}, iN = {0,0,0,0}, hN = {0,0,0,0};
#pragma unroll
      for (int kf = 0; kf < 2; ++kf) {
        bf16x8 gh = *(const bf16x8*)&h0n[kf * 1024 + rdb];
        bf16x8 gl = *(const bf16x8*)&h0n[kf * 1024 + 512 + rdb];
        bf16x8 qh = *(const bf16x8*)&h1o[kf * 1024 + rdb];
        bf16x8 ql = *(const bf16x8*)&h1o[kf * 1024 + 512 + rdb];
        cR = mfma16(gh, wB[1][0][kf][0], cR);
        cR = mfma16(qh, wB[2][0][kf][0], cR);
        cZ = mfma16(gh, wB[1][1][kf][0], cZ);
        cZ = mfma16(qh, wB[2][1][kf][0], cZ);
        iN = mfma16(gh, wB[1][2][kf][0], iN);
        hN = mfma16(qh, wB[2][2][kf][0], hN);
        cR = mfma16(gl, wB[1][0][kf][0], cR);
        cR = mfma16(ql, wB[2][0][kf][0], cR);
        cZ = mfma16(gl, wB[1][1][kf][0], cZ);
        cZ = mfma16(ql, wB[2][1][kf][0], cZ);
        iN = mfma16(gl, wB[1][2][kf][0], iN);
        hN = mfma16(ql, wB[2][2][kf][0], hN);
        cR = mfma16(gh, wB[1][0][kf][1], cR);
        cR = mfma16(qh, wB[2][0][kf][1], cR);
        cZ = mfma16(gh, wB[1][1][kf][1], cZ);
        cZ = mfma16(qh, wB[2][1][kf][1], cZ);
        iN = mfma16(gh, wB[1][2][kf][1], iN);
        hN = mfma16(qh, wB[2][2][kf][1], hN);
      }
      // ---- gate1 (lane-local), publish h1(new) frags, decoder partials ----
      unsigned short* h1n = aH1[cur];
      float v[4];
#pragma unroll
      for (int i = 0; i < 4; ++i) {
        float r = sgm(cR[i] + bi1[0] + bh1[0]);
        float z = sgm(cZ[i] + bi1[1] + bh1[1]);
        float n = th(iN[i] + bi1[2] + r * (bh1[2] + hN[i]));
        h1own[i] = (1.f - z) * n + z * h1own[i];
        unsigned short hi = rbf(h1own[i]);
        unsigned short lo = rbf(h1own[i] - ubf(hi));
        int idx = wbase + (((rg * 4 + i) ^ rgj) << 3);
        h1n[idx] = hi; h1n[idx + 512] = lo;
        v[i] = oW * h1own[i];
      }
      if (ph == 1) {
        // intra-wave reduce over the 16 jc lanes (j covers 16w..16w+15)
#pragma unroll
        for (int off = 1; off < 16; off <<= 1)
#pragma unroll
          for (int i = 0; i < 4; ++i) v[i] += __shfl_xor(v[i], off, 64);
        if (jc == 0) {
#pragma unroll
          for (int i = 0; i < 4; ++i) pw[w][rg * 4 + i] = v[i];
        }
      }
      __syncthreads();   // end: h1(new) frags + pw complete
    }
    // ---- decoder tail: emit out[179] from last partials ----
    if (ph == 1) {
      if (w == 0 && jc == 0) {
#pragma unroll
        for (int i = 0; i < 4; ++i) {
          float fv = ob + pw[0][rg * 4 + i] + pw[1][rg * 4 + i]
                        + pw[2][rg * 4 + i] + pw[3][rg * 4 + i];
          p.out[(size_t)(b0 + rg * 4 + i) * 180 + 179] = fv;
        }
      }
    }
  }
}

extern "C" void kernel_launch(void* const* d_in, const int* in_sizes, int n_in,
                              void* d_out, int out_size, void* d_ws, size_t ws_size,
                              hipStream_t stream) {
  // input order: 0 x, 1 enc_Wih0, 2 enc_Whh0, 3 enc_bih0, 4 enc_bhh0,
  // 5 enc_Wih1, 6 enc_Whh1, 7 enc_bih1, 8 enc_bhh1, 9 dec_Wih0, 10 dec_Whh0,
  // 11 dec_bih0, 12 dec_bhh0, 13 dec_Wih1, 14 dec_Whh1, 15 dec_bih1,
  // 16 dec_bhh1, 17 out_W, 18 out_b
  unsigned short* wt = (unsigned short*)d_ws;  // 6*24576*2 = 294912 B

  prep_w<<<dim3(6), dim3(256), 0, stream>>>(
      (const float*)d_in[2], (const float*)d_in[5], (const float*)d_in[6],
      (const float*)d_in[10], (const float*)d_in[13], (const float*)d_in[14], wt);

  Params p;
  p.x = (const float*)d_in[0];
  p.wih0e = (const float*)d_in[1];
  p.bih0e = (const float*)d_in[3];
  p.bhh0e = (const float*)d_in[4];
  p.bih1e = (const float*)d_in[7];
  p.bhh1e = (const float*)d_in[8];
  p.wih0d = (const float*)d_in[9];
  p.bih0d = (const float*)d_in[11];
  p.bhh0d = (const float*)d_in[12];
  p.bih1d = (const float*)d_in[15];
  p.bhh1d = (const float*)d_in[16];
  p.outW = (const float*)d_in[17];
  p.outb = (const float*)d_in[18];
  p.wt = wt;
  p.out = (float*)d_out;

  gru_main<<<dim3(512), dim3(256), 0, stream>>>(p);
}